// Round 4
// baseline (492.280 us; speedup 1.0000x reference)
//
#include <hip/hip_runtime.h>

typedef unsigned short u16;
typedef unsigned int u32;
typedef __attribute__((ext_vector_type(8))) u16 u16x8;
typedef __attribute__((ext_vector_type(8))) __bf16 bf16x8;
typedef __attribute__((ext_vector_type(4))) float f32x4;

#define CIN 128
#define NB 4
#define NN 4096
#define KPTS 16
#define COUT 256
#define POSB 65536      // NN*KPTS
#define TOTPOS 262144   // NB*POSB
#define CK 2304         // 9*256

__device__ __forceinline__ float bf2f(u16 u){ return __uint_as_float(((u32)u)<<16); }
__device__ __forceinline__ u16 f2bf(float f){
  u32 u = __float_as_uint(f);
  u32 r = (u + 0x7fffu + ((u>>16)&1u)) >> 16;   // RNE
  return (u16)r;
}

// ---- 1. pack conv_w with the U/V transform:
//   out = Wl@x_i + Wr@(x_j-x_i) = (Wl-Wr)@x_i + Wr@x_j
//   wp[co][tap*256 + c]:  c<128 -> U = Wl-Wr;  c>=128 -> V = Wr
__global__ void pack_w_kernel(const float* __restrict__ w, u16* __restrict__ wp){
  int t = blockIdx.x*256 + threadIdx.x;
  if (t >= COUT*CK) return;
  int co = t / CK; int r = t - co*CK; int tap = r >> 8; int c = r & 255;
  float v;
  if (c < 128)
    v = w[(co*256 + c)*9 + tap] - w[(co*256 + 128 + c)*9 + tap];
  else
    v = w[(co*256 + c)*9 + tap];
  wp[t] = f2bf(v);
}

// ---- 2. transpose+cast x,y [B][128][4096] f32 -> xt,yt [B][4096][128] bf16
__global__ void transpose_cast_kernel(const float* __restrict__ x, const float* __restrict__ y,
                                      u16* __restrict__ xt, u16* __restrict__ yt){
  __shared__ u16 tile[2][32][65];
  int n0 = blockIdx.x*64, c0 = blockIdx.y*32, b = blockIdx.z;
  int t = threadIdx.x;
  int tn = t & 63, tc = t >> 6;
  #pragma unroll
  for (int i=0;i<8;++i){
    int c = tc*8 + i;
    size_t src = ((size_t)(b*CIN + c0 + c))*NN + n0 + tn;
    tile[0][c][tn] = f2bf(x[src]);
    tile[1][c][tn] = f2bf(y[src]);
  }
  __syncthreads();
  int tcc = t & 31, tnn = t >> 5;
  #pragma unroll
  for (int i=0;i<8;++i){
    int n = tnn*8 + i;
    size_t dst = ((size_t)(b*NN + n0 + n))*CIN + c0 + tcc;
    xt[dst] = tile[0][tcc][n];
    yt[dst] = tile[1][tcc][n];
  }
}

// element offset into a [row][32] bf16 tile with 16B-chunk XOR swizzle (read side)
#define SWZ(row, chunk) (((row)*32) + ((((chunk) ^ (((row)>>1)&3))) << 3))

// ---- 3. fused gather + implicit-GEMM conv + bias + (max over k) + BN stats
// Staging via global_load_lds: LDS dest linear (wave-uniform base + lane*16),
// per-lane SOURCE pre-swizzled so data lands at SWZ position (m173 pattern).
__global__ __launch_bounds__(256) void conv_gemm_kernel(const u16* __restrict__ wp,
    const int* __restrict__ e, const u16* __restrict__ xt, const u16* __restrict__ yt,
    const u16* __restrict__ zrow, const float* __restrict__ bias,
    float* __restrict__ ssum, float* __restrict__ ssq, float* __restrict__ maxout){
  __shared__ u16 alds[2][4096];
  __shared__ u16 blds[2][4096];

  int bid = blockIdx.x;
  int co_half = (bid >> 3) & 1;                      // pair same-ptile blocks 8 apart (same XCD)
  int ptile = (bid & 7) | ((bid >> 4) << 3);         // 0..2047
  int p0 = ptile * 128;
  int b = p0 >> 16;
  int pib0 = p0 & (POSB-1);
  int nb0 = pib0 >> 4;

  int t = threadIdx.x;
  int lane = t & 63, wave = t >> 6;
  int wr = wave >> 1, wc = wave & 1;
  int co_base = co_half*128;

  // staging geometry: lane l, instr i covers LDS bytes w*2048+i*1024+l*16
  //   -> row = w*32+i*16+(l>>2), logical chunk = (l&3)^((row>>1)&3)
  int r0 = wave*32 + (lane>>2);
  int r1 = r0 + 16;
  int ch0 = (lane&3) ^ ((r0>>1)&3);
  int ch1 = (lane&3) ^ ((r1>>1)&3);
  int wu = __builtin_amdgcn_readfirstlane(wave) * 1024;   // element offset of wave's LDS slice

  const u16* pA0 = wp + (size_t)(co_base + r0)*CK + ch0*8;
  const u16* pA1 = wp + (size_t)(co_base + r1)*CK + ch1*8;

  const int* ep0 = e + p0;                 // edge_index[0] plane (x_j from y)
  const int* ep1 = ep0 + TOTPOS;           // edge_index[1] plane (x_i from x)
  const u16* xb = xt + ((size_t)b)*NN*CIN;
  const u16* yb = yt + ((size_t)b)*NN*CIN;

  int pr0 = pib0 + r0, pr1 = pib0 + r1;
  int n_r0 = pr0 >> 4, k_r0 = pr0 & 15;
  int n_r1 = pr1 >> 4, k_r1 = pr1 & 15;

  // per-tap gather pointers for this lane's two rows
  auto TAPP = [&](int tap, const u16*& qx0, const u16*& qy0, const u16*& qx1, const u16*& qy1){
    int tdiv3 = (tap*11) >> 5;             // tap/3 for tap in [0,9)
    int dn = tdiv3 - 1, dk = tap - tdiv3*3 - 1;
    int doff = dn*16 + dk;
    bool v0 = ((unsigned)(n_r0+dn) < (unsigned)NN) & ((unsigned)(k_r0+dk) < (unsigned)KPTS);
    bool v1 = ((unsigned)(n_r1+dn) < (unsigned)NN) & ((unsigned)(k_r1+dk) < (unsigned)KPTS);
    int j1_0=0, j0_0=0, j1_1=0, j0_1=0;
    if (v0){ j1_0 = ep1[r0+doff]; j0_0 = ep0[r0+doff]; }
    if (v1){ j1_1 = ep1[r1+doff]; j0_1 = ep0[r1+doff]; }
    qx0 = (v0 ? xb + (size_t)j1_0*CIN : zrow) + ch0*8;
    qy0 = (v0 ? yb + (size_t)j0_0*CIN : zrow) + ch0*8;
    qx1 = (v1 ? xb + (size_t)j1_1*CIN : zrow) + ch1*8;
    qy1 = (v1 ? yb + (size_t)j0_1*CIN : zrow) + ch1*8;
  };

  auto G16 = [&](const u16* g, u16* l){
    __builtin_amdgcn_global_load_lds((const __attribute__((address_space(1))) u32*)g,
                                     (__attribute__((address_space(3))) u32*)l, 16, 0, 0);
  };
  auto STAGE = [&](int nbuf, const u16* A0, const u16* A1, const u16* B0, const u16* B1){
    G16(A0, &alds[nbuf][wu]);
    G16(A1, &alds[nbuf][wu + 512]);
    G16(B0, &blds[nbuf][wu]);
    G16(B1, &blds[nbuf][wu + 512]);
  };

  f32x4 acc[4][4];
  #pragma unroll
  for (int i=0;i<4;++i)
    #pragma unroll
    for (int j=0;j<4;++j) acc[i][j] = (f32x4){0.f,0.f,0.f,0.f};

  const u16 *px0,*py0,*px1,*py1, *qx0,*qy0,*qx1,*qy1;
  TAPP(0, px0,py0,px1,py1);
  STAGE(0, pA0, pA1, px0, px1);
  __syncthreads();

  int l15 = lane & 15, l4 = lane >> 4;
  int aoff[4], boff[4];
  #pragma unroll
  for (int f=0; f<4; ++f){
    aoff[f] = SWZ(wr*64 + f*16 + l15, l4);
    boff[f] = SWZ(wc*64 + f*16 + l15, l4);
  }

  for (int tap = 0; tap < 9; ++tap){
    if (tap < 8) TAPP(tap+1, qx0,qy0,qx1,qy1);     // pointers ready 8 steps ahead
    #pragma unroll
    for (int cg = 0; cg < 8; ++cg){
      int cur = cg & 1;                            // tap*8 even -> parity = cg&1
      bool has_next = (tap < 8) || (cg < 7);
      if (has_next){
        if (cg < 7){
          int ncg = cg + 1;
          const u16* B0 = (ncg < 4 ? px0 : py0) + (ncg & 3)*32;
          const u16* B1 = (ncg < 4 ? px1 : py1) + (ncg & 3)*32;
          STAGE(cur^1, pA0 + ncg*32, pA1 + ncg*32, B0, B1);
        } else {
          STAGE(cur^1, pA0 + 256, pA1 + 256, qx0, qx1);   // next tap, cg=0 (x-part)
        }
      }
      bf16x8 af[4], bfv[4];
      #pragma unroll
      for (int f=0; f<4; ++f){
        af[f]  = *(bf16x8*)&alds[cur][aoff[f]];
        bfv[f] = *(bf16x8*)&blds[cur][boff[f]];
      }
      #pragma unroll
      for (int fm=0; fm<4; ++fm)
        #pragma unroll
        for (int fn=0; fn<4; ++fn)
          acc[fm][fn] = __builtin_amdgcn_mfma_f32_16x16x32_bf16(af[fm], bfv[fn], acc[fm][fn], 0, 0, 0);
      __syncthreads();
    }
    px0=qx0; py0=qy0; px1=qx1; py1=qy1;
    pA0 += 256; pA1 += 256;
  }

  // ---- epilogue: bias + max over k (l15) + per-channel sum/sumsq
  float* fs = (float*)&alds[0][0];       // fs[0..128) = sum, fs[128..256) = sumsq
  fs[t & 255] = 0.f;
  __syncthreads();

  #pragma unroll
  for (int fm=0; fm<4; ++fm){
    #pragma unroll
    for (int j=0; j<4; ++j){
      int ch = wr*64 + fm*16 + l4*4 + j;
      int co_g = co_base + ch;
      float bv = bias[co_g];
      float s = 0.f, q = 0.f;
      float mv[4];
      #pragma unroll
      for (int fn=0; fn<4; ++fn){
        float v = acc[fm][fn][j] + bv;
        s += v; q += v*v; mv[fn] = v;
      }
      #pragma unroll
      for (int o=1; o<16; o<<=1){
        s += __shfl_xor(s, o, 64);
        q += __shfl_xor(q, o, 64);
        #pragma unroll
        for (int fn=0; fn<4; ++fn) mv[fn] = fmaxf(mv[fn], __shfl_xor(mv[fn], o, 64));
      }
      if (l15 == 0){
        atomicAdd(&fs[ch], s);
        atomicAdd(&fs[128 + ch], q);
        size_t rowb = ((size_t)(b*COUT + co_g)) << 12;
        #pragma unroll
        for (int fn=0; fn<4; ++fn)
          maxout[rowb + nb0 + wc*4 + fn] = mv[fn];
      }
    }
  }
  __syncthreads();
  if (t < 128)      atomicAdd(&ssum[co_base + t], fs[t]);
  else if (t < 256) atomicAdd(&ssq[co_base + t - 128], fs[t]);
}

// ---- 4. finalize BN scale/shift
__global__ void finalize_stats_kernel(const float* __restrict__ ssum, const float* __restrict__ ssq,
                                      const float* __restrict__ gamma, const float* __restrict__ beta,
                                      float* __restrict__ scale, float* __restrict__ shift){
  int co = threadIdx.x;
  float inv = 1.0f / (float)TOTPOS;
  float mean = ssum[co]*inv;
  float var = ssq[co]*inv - mean*mean;
  float sc = gamma[co] * rsqrtf(var + 1e-5f);
  scale[co] = sc;
  shift[co] = beta[co] - mean*sc;
}

// ---- 5. in-place BN + ReLU on maxout (valid since scale>0: max/relu commute with affine)
__global__ void bn_finish_kernel(float* __restrict__ out, const float* __restrict__ scale,
                                 const float* __restrict__ shift){
  int t = blockIdx.x*256 + threadIdx.x;              // (b*COUT+co)*NN + n
  int co = (t >> 12) & 255;
  float v = out[t];
  out[t] = fmaxf(fmaf(scale[co], v, shift[co]), 0.f);
}

extern "C" void kernel_launch(void* const* d_in, const int* in_sizes, int n_in,
                              void* d_out, int out_size, void* d_ws, size_t ws_size,
                              hipStream_t stream){
  const float* x = (const float*)d_in[0];
  const float* y = (const float*)d_in[1];
  const int*   e = (const int*)d_in[2];
  const float* w = (const float*)d_in[3];
  const float* bias = (const float*)d_in[4];
  const float* gamma = (const float*)d_in[5];
  const float* beta  = (const float*)d_in[6];
  float* out = (float*)d_out;

  char* ws = (char*)d_ws;                  // total footprint: ~9.6 MB
  u16*   wp    = (u16*)(ws);               // 1,179,648 B
  float* ssum  = (float*)(ws + 1179648);   // 1 KB
  float* ssq   = (float*)(ws + 1180672);   // 1 KB
  u16*   zrow  = (u16*)(ws + 1181696);     // 1 KB zero row
  float* scale = (float*)(ws + 1182720);   // 1 KB
  float* shift = (float*)(ws + 1183744);   // 1 KB
  u16*   xt    = (u16*)(ws + 1184768);     // 4 MB
  u16*   yt    = (u16*)(ws + 5379072);     // 4 MB  (end: 9,573,376)

  hipMemsetAsync(ssum, 0, 3072, stream);   // zero ssum+ssq+zrow every call (deterministic)

  pack_w_kernel<<<2304, 256, 0, stream>>>(w, wp);
  dim3 tg(NN/64, CIN/32, NB);
  transpose_cast_kernel<<<tg, 256, 0, stream>>>(x, y, xt, yt);
  conv_gemm_kernel<<<4096, 256, 0, stream>>>(wp, e, xt, yt, zrow, bias, ssum, ssq, out);
  finalize_stats_kernel<<<1, COUT, 0, stream>>>(ssum, ssq, gamma, beta, scale, shift);
  bn_finish_kernel<<<out_size/256, 256, 0, stream>>>(out, scale, shift);
}

// Round 5
// 435.272 us; speedup vs baseline: 1.1310x; 1.1310x over previous
//
#include <hip/hip_runtime.h>

typedef unsigned short u16;
typedef unsigned int u32;
typedef __attribute__((ext_vector_type(8))) u16 u16x8;
typedef __attribute__((ext_vector_type(8))) __bf16 bf16x8;
typedef __attribute__((ext_vector_type(4))) float f32x4;

#define CIN 128
#define NB 4
#define NN 4096
#define KPTS 16
#define COUT 256
#define POSB 65536      // NN*KPTS
#define TOTPOS 262144   // NB*POSB
#define CK 2304         // 9*256

__device__ __forceinline__ float bf2f(u16 u){ return __uint_as_float(((u32)u)<<16); }
__device__ __forceinline__ u16 f2bf(float f){
  u32 u = __float_as_uint(f);
  u32 r = (u + 0x7fffu + ((u>>16)&1u)) >> 16;   // RNE
  return (u16)r;
}

// ---- 1. pack conv_w with the U/V transform:
//   out = Wl@x_i + Wr@(x_j-x_i) = (Wl-Wr)@x_i + Wr@x_j
__global__ void pack_w_kernel(const float* __restrict__ w, u16* __restrict__ wp){
  int t = blockIdx.x*256 + threadIdx.x;
  if (t >= COUT*CK) return;
  int co = t / CK; int r = t - co*CK; int tap = r >> 8; int c = r & 255;
  float v;
  if (c < 128)
    v = w[(co*256 + c)*9 + tap] - w[(co*256 + 128 + c)*9 + tap];
  else
    v = w[(co*256 + c)*9 + tap];
  wp[t] = f2bf(v);
}

// ---- 2. transpose+cast x,y [B][128][4096] f32 -> xt,yt [B][4096][128] bf16
__global__ void transpose_cast_kernel(const float* __restrict__ x, const float* __restrict__ y,
                                      u16* __restrict__ xt, u16* __restrict__ yt){
  __shared__ u16 tile[2][32][65];
  int n0 = blockIdx.x*64, c0 = blockIdx.y*32, b = blockIdx.z;
  int t = threadIdx.x;
  int tn = t & 63, tc = t >> 6;
  #pragma unroll
  for (int i=0;i<8;++i){
    int c = tc*8 + i;
    size_t src = ((size_t)(b*CIN + c0 + c))*NN + n0 + tn;
    tile[0][c][tn] = f2bf(x[src]);
    tile[1][c][tn] = f2bf(y[src]);
  }
  __syncthreads();
  int tcc = t & 31, tnn = t >> 5;
  #pragma unroll
  for (int i=0;i<8;++i){
    int n = tnn*8 + i;
    size_t dst = ((size_t)(b*NN + n0 + n))*CIN + c0 + tcc;
    xt[dst] = tile[0][tcc][n];
    yt[dst] = tile[1][tcc][n];
  }
}

// element offset into a [row][32] bf16 tile with 16B-chunk XOR swizzle (read side)
#define SWZ(row, chunk) (((row)*32) + ((((chunk) ^ (((row)>>1)&3))) << 3))

// ---- 3. fused gather + implicit-GEMM conv + bias + (max over k) + BN stats
// gload_lds staging, 3-deep pipeline, counted vmcnt (T3+T4), raw barriers.
__global__ __launch_bounds__(256) void conv_gemm_kernel(const u16* __restrict__ wp,
    const int* __restrict__ e, const u16* __restrict__ xt, const u16* __restrict__ yt,
    const u16* __restrict__ zrow, const float* __restrict__ bias,
    float* __restrict__ ssum, float* __restrict__ ssq, float* __restrict__ maxout){
  __shared__ u16 als[3*4096];
  __shared__ u16 bls[3*4096];

  int bid = blockIdx.x;
  int co_half = (bid >> 3) & 1;
  int ptile = (bid & 7) | ((bid >> 4) << 3);
  int p0 = ptile * 128;
  int b = p0 >> 16;
  int pib0 = p0 & (POSB-1);
  int nb0 = pib0 >> 4;

  int t = threadIdx.x;
  int lane = t & 63, wave = t >> 6;
  int wr = wave >> 1, wc = wave & 1;
  int co_base = co_half*128;

  // staging geometry: lane l, instr i covers LDS elements wave*1024+i*512+l*8
  //   -> row = wave*32+i*16+(l>>2), logical chunk = (l&3)^((row>>1)&3)
  int r0 = wave*32 + (lane>>2);
  int r1 = r0 + 16;
  int ch0 = (lane&3) ^ ((r0>>1)&3);
  int ch1 = (lane&3) ^ ((r1>>1)&3);
  int wu = __builtin_amdgcn_readfirstlane(wave) * 1024;

  const u16* pA0 = wp + (size_t)(co_base + r0)*CK + ch0*8;
  const u16* pA1 = wp + (size_t)(co_base + r1)*CK + ch1*8;

  const int* ep0 = e + p0;                 // edge_index[0] (x_j from y)
  const int* ep1 = ep0 + TOTPOS;           // edge_index[1] (x_i from x)
  const u16* xb = xt + ((size_t)b)*NN*CIN;
  const u16* yb = yt + ((size_t)b)*NN*CIN;

  int pr0 = pib0 + r0, pr1 = pib0 + r1;
  int n_r0 = pr0 >> 4, k_r0 = pr0 & 15;
  int n_r1 = pr1 >> 4, k_r1 = pr1 & 15;

  auto TAPP = [&](int tap, const u16*& ox0, const u16*& oy0, const u16*& ox1, const u16*& oy1){
    int tdiv3 = (tap*11) >> 5;
    int dn = tdiv3 - 1, dk = tap - tdiv3*3 - 1;
    int doff = dn*16 + dk;
    bool v0 = ((unsigned)(n_r0+dn) < (unsigned)NN) & ((unsigned)(k_r0+dk) < (unsigned)KPTS);
    bool v1 = ((unsigned)(n_r1+dn) < (unsigned)NN) & ((unsigned)(k_r1+dk) < (unsigned)KPTS);
    int j1_0=0, j0_0=0, j1_1=0, j0_1=0;
    if (v0){ j1_0 = ep1[r0+doff]; j0_0 = ep0[r0+doff]; }
    if (v1){ j1_1 = ep1[r1+doff]; j0_1 = ep0[r1+doff]; }
    ox0 = (v0 ? xb + (size_t)j1_0*CIN : zrow) + ch0*8;
    oy0 = (v0 ? yb + (size_t)j0_0*CIN : zrow) + ch0*8;
    ox1 = (v1 ? xb + (size_t)j1_1*CIN : zrow) + ch1*8;
    oy1 = (v1 ? yb + (size_t)j0_1*CIN : zrow) + ch1*8;
  };

  auto G16 = [&](const u16* g, u16* l){
    __builtin_amdgcn_global_load_lds((const __attribute__((address_space(1))) u32*)g,
                                     (__attribute__((address_space(3))) u32*)l, 16, 0, 0);
  };

  f32x4 acc[4][4];
  #pragma unroll
  for (int i=0;i<4;++i)
    #pragma unroll
    for (int j=0;j<4;++j) acc[i][j] = (f32x4){0.f,0.f,0.f,0.f};

  const u16 *px0,*py0,*px1,*py1;
  const u16 *qx0=zrow,*qy0=zrow,*qx1=zrow,*qy1=zrow;
  TAPP(0, px0,py0,px1,py1);

  // prologue: stages 0,1,2 (tap0 chunks 0,1,2 = x-part) into bufs 0,1,2
  G16(pA0,    &als[wu]);        G16(pA1,    &als[wu+512]);
  G16(px0,    &bls[wu]);        G16(px1,    &bls[wu+512]);
  G16(pA0+32, &als[4096+wu]);   G16(pA1+32, &als[4096+wu+512]);
  G16(px0+32, &bls[4096+wu]);   G16(px1+32, &bls[4096+wu+512]);
  G16(pA0+64, &als[8192+wu]);   G16(pA1+64, &als[8192+wu+512]);
  G16(px0+64, &bls[8192+wu]);   G16(px1+64, &bls[8192+wu+512]);

  int l15 = lane & 15, l4 = lane >> 4;
  int aoff[4], boff[4];
  #pragma unroll
  for (int f=0; f<4; ++f){
    aoff[f] = SWZ(wr*64 + f*16 + l15, l4);
    boff[f] = SWZ(wc*64 + f*16 + l15, l4);
  }

  int off = 0;                                    // current buffer element offset
  const u16* pAs0 = pA0 + 96;                     // A src for stage s=3
  const u16* pAs1 = pA1 + 96;

  auto STEP = [&](int tap, int cg, int vmsel){
    if (vmsel == 8)      asm volatile("s_waitcnt vmcnt(8)" ::: "memory");
    else if (vmsel == 4) asm volatile("s_waitcnt vmcnt(4)" ::: "memory");
    else                 asm volatile("s_waitcnt vmcnt(0)" ::: "memory");
    __builtin_amdgcn_s_barrier();                 // buf[k%3] ready (each wave waited its own)
    bf16x8 af[4], bfv[4];
    #pragma unroll
    for (int f=0; f<4; ++f){
      af[f]  = *(bf16x8*)&als[off + aoff[f]];
      bfv[f] = *(bf16x8*)&bls[off + boff[f]];
    }
    asm volatile("s_waitcnt lgkmcnt(0)" ::: "memory");
    __builtin_amdgcn_sched_barrier(0);
    __builtin_amdgcn_s_barrier();                 // all waves done reading -> safe to overwrite
    int s = tap*8 + cg + 3;
    if (s < 72){
      const u16 *B0, *B1;
      switch (cg){                                 // chunk (s&7): 3,4,5,6,7 -> cur tap; 0,1,2 -> next
        case 0:  B0 = px0+96; B1 = px1+96; break;
        case 1:  B0 = py0;    B1 = py1;    break;
        case 2:  B0 = py0+32; B1 = py1+32; break;
        case 3:  B0 = py0+64; B1 = py1+64; break;
        case 4:  B0 = py0+96; B1 = py1+96; break;
        case 5:  B0 = qx0;    B1 = qx1;    break;
        case 6:  B0 = qx0+32; B1 = qx1+32; break;
        default: B0 = qx0+64; B1 = qx1+64; break;
      }
      G16(pAs0 + cg*32, &als[off+wu]);
      G16(pAs1 + cg*32, &als[off+wu+512]);
      G16(B0, &bls[off+wu]);
      G16(B1, &bls[off+wu+512]);
    }
    if (cg == 2 && tap < 8) TAPP(tap+1, qx0,qy0,qx1,qy1);   // e-loads enqueued after stage
    __builtin_amdgcn_s_setprio(1);
    #pragma unroll
    for (int fm=0; fm<4; ++fm)
      #pragma unroll
      for (int fn=0; fn<4; ++fn)
        acc[fm][fn] = __builtin_amdgcn_mfma_f32_16x16x32_bf16(af[fm], bfv[fn], acc[fm][fn], 0, 0, 0);
    __builtin_amdgcn_s_setprio(0);
    off = (off == 8192) ? 0 : off + 4096;
  };

  for (int tap = 0; tap < 8; ++tap){
    #pragma unroll
    for (int cg = 0; cg < 8; ++cg) STEP(tap, cg, 8);
    px0=qx0; py0=qy0; px1=qx1; py1=qy1;
    pAs0 += 256; pAs1 += 256;
  }
  #pragma unroll
  for (int cg = 0; cg < 8; ++cg) STEP(8, cg, cg < 6 ? 8 : (cg == 6 ? 4 : 0));

  // ---- epilogue: bias + max over k (l15) + per-channel sum/sumsq
  float* fs = (float*)&als[0];           // fs[0..128) = sum, fs[128..256) = sumsq
  fs[t & 255] = 0.f;
  __syncthreads();

  #pragma unroll
  for (int fm=0; fm<4; ++fm){
    #pragma unroll
    for (int j=0; j<4; ++j){
      int ch = wr*64 + fm*16 + l4*4 + j;
      int co_g = co_base + ch;
      float bv = bias[co_g];
      float s = 0.f, q = 0.f;
      float mv[4];
      #pragma unroll
      for (int fn=0; fn<4; ++fn){
        float v = acc[fm][fn][j] + bv;
        s += v; q += v*v; mv[fn] = v;
      }
      #pragma unroll
      for (int o=1; o<16; o<<=1){
        s += __shfl_xor(s, o, 64);
        q += __shfl_xor(q, o, 64);
        #pragma unroll
        for (int fn=0; fn<4; ++fn) mv[fn] = fmaxf(mv[fn], __shfl_xor(mv[fn], o, 64));
      }
      if (l15 == 0){
        atomicAdd(&fs[ch], s);
        atomicAdd(&fs[128 + ch], q);
        size_t rowb = ((size_t)(b*COUT + co_g)) << 12;
        #pragma unroll
        for (int fn=0; fn<4; ++fn)
          maxout[rowb + nb0 + wc*4 + fn] = mv[fn];
      }
    }
  }
  __syncthreads();
  if (t < 128)      atomicAdd(&ssum[co_base + t], fs[t]);
  else if (t < 256) atomicAdd(&ssq[co_base + t - 128], fs[t]);
}

// ---- 4. finalize BN scale/shift
__global__ void finalize_stats_kernel(const float* __restrict__ ssum, const float* __restrict__ ssq,
                                      const float* __restrict__ gamma, const float* __restrict__ beta,
                                      float* __restrict__ scale, float* __restrict__ shift){
  int co = threadIdx.x;
  float inv = 1.0f / (float)TOTPOS;
  float mean = ssum[co]*inv;
  float var = ssq[co]*inv - mean*mean;
  float sc = gamma[co] * rsqrtf(var + 1e-5f);
  scale[co] = sc;
  shift[co] = beta[co] - mean*sc;
}

// ---- 5. in-place BN + ReLU on maxout (valid since scale>0)
__global__ void bn_finish_kernel(float* __restrict__ out, const float* __restrict__ scale,
                                 const float* __restrict__ shift){
  int t = blockIdx.x*256 + threadIdx.x;
  int co = (t >> 12) & 255;
  float v = out[t];
  out[t] = fmaxf(fmaf(scale[co], v, shift[co]), 0.f);
}

extern "C" void kernel_launch(void* const* d_in, const int* in_sizes, int n_in,
                              void* d_out, int out_size, void* d_ws, size_t ws_size,
                              hipStream_t stream){
  const float* x = (const float*)d_in[0];
  const float* y = (const float*)d_in[1];
  const int*   e = (const int*)d_in[2];
  const float* w = (const float*)d_in[3];
  const float* bias = (const float*)d_in[4];
  const float* gamma = (const float*)d_in[5];
  const float* beta  = (const float*)d_in[6];
  float* out = (float*)d_out;

  char* ws = (char*)d_ws;                  // total footprint: ~9.6 MB
  u16*   wp    = (u16*)(ws);               // 1,179,648 B
  float* ssum  = (float*)(ws + 1179648);   // 1 KB
  float* ssq   = (float*)(ws + 1180672);   // 1 KB
  u16*   zrow  = (u16*)(ws + 1181696);     // 1 KB zero row
  float* scale = (float*)(ws + 1182720);   // 1 KB
  float* shift = (float*)(ws + 1183744);   // 1 KB
  u16*   xt    = (u16*)(ws + 1184768);     // 4 MB
  u16*   yt    = (u16*)(ws + 5379072);     // 4 MB  (end: 9,573,376)

  hipMemsetAsync(ssum, 0, 3072, stream);   // zero ssum+ssq+zrow every call (deterministic)

  pack_w_kernel<<<2304, 256, 0, stream>>>(w, wp);
  dim3 tg(NN/64, CIN/32, NB);
  transpose_cast_kernel<<<tg, 256, 0, stream>>>(x, y, xt, yt);
  conv_gemm_kernel<<<4096, 256, 0, stream>>>(wp, e, xt, yt, zrow, bias, ssum, ssq, out);
  finalize_stats_kernel<<<1, COUT, 0, stream>>>(ssum, ssq, gamma, beta, scale, shift);
  bn_finish_kernel<<<out_size/256, 256, 0, stream>>>(out, scale, shift);
}

// Round 6
// 350.327 us; speedup vs baseline: 1.4052x; 1.2425x over previous
//
#include <hip/hip_runtime.h>

typedef unsigned short u16;
typedef unsigned int u32;
typedef __attribute__((ext_vector_type(8))) u16 u16x8;
typedef __attribute__((ext_vector_type(8))) __bf16 bf16x8;
typedef __attribute__((ext_vector_type(4))) float f32x4;

#define CIN 128
#define NB 4
#define NN 4096
#define KPTS 16
#define COUT 256
#define POSB 65536      // NN*KPTS
#define TOTPOS 262144   // NB*POSB
#define CK 2304         // 9*256

__device__ __forceinline__ float bf2f(u16 u){ return __uint_as_float(((u32)u)<<16); }
__device__ __forceinline__ u16 f2bf(float f){
  u32 u = __float_as_uint(f);
  u32 r = (u + 0x7fffu + ((u>>16)&1u)) >> 16;   // RNE
  return (u16)r;
}

// ---- 1. pack conv_w with the U/V transform:
//   out = Wl@x_i + Wr@(x_j-x_i) = (Wl-Wr)@x_i + Wr@x_j
__global__ void pack_w_kernel(const float* __restrict__ w, u16* __restrict__ wp){
  int t = blockIdx.x*256 + threadIdx.x;
  if (t >= COUT*CK) return;
  int co = t / CK; int r = t - co*CK; int tap = r >> 8; int c = r & 255;
  float v;
  if (c < 128)
    v = w[(co*256 + c)*9 + tap] - w[(co*256 + 128 + c)*9 + tap];
  else
    v = w[(co*256 + c)*9 + tap];
  wp[t] = f2bf(v);
}

// ---- 2. transpose+cast x,y [B][128][4096] f32 -> xt,yt [B][4096][128] bf16
__global__ void transpose_cast_kernel(const float* __restrict__ x, const float* __restrict__ y,
                                      u16* __restrict__ xt, u16* __restrict__ yt){
  __shared__ u16 tile[2][32][65];
  int n0 = blockIdx.x*64, c0 = blockIdx.y*32, b = blockIdx.z;
  int t = threadIdx.x;
  int tn = t & 63, tc = t >> 6;
  #pragma unroll
  for (int i=0;i<8;++i){
    int c = tc*8 + i;
    size_t src = ((size_t)(b*CIN + c0 + c))*NN + n0 + tn;
    tile[0][c][tn] = f2bf(x[src]);
    tile[1][c][tn] = f2bf(y[src]);
  }
  __syncthreads();
  int tcc = t & 31, tnn = t >> 5;
  #pragma unroll
  for (int i=0;i<8;++i){
    int n = tnn*8 + i;
    size_t dst = ((size_t)(b*NN + n0 + n))*CIN + c0 + tcc;
    xt[dst] = tile[0][tcc][n];
    yt[dst] = tile[1][tcc][n];
  }
}

// element offset into a [row][32] bf16 tile with 16B-chunk XOR swizzle (read side)
#define SWZ(row, chunk) (((row)*32) + ((((chunk) ^ (((row)>>1)&3))) << 3))

// ---- 3. fused panel-gather + implicit-GEMM conv + bias + (max over k) + BN stats
// H-panel: per block, the 10 n's x 18 k's window of H rows (192 padded) is staged
// ONCE per 32-channel chunk; all 9 taps read it via contiguous ds_reads.
__global__ __launch_bounds__(256) void conv_gemm_kernel(const u16* __restrict__ wp,
    const int* __restrict__ e, const u16* __restrict__ xt, const u16* __restrict__ yt,
    const u16* __restrict__ zrow, const float* __restrict__ bias,
    float* __restrict__ ssum, float* __restrict__ ssq, float* __restrict__ maxout){
  __shared__ u16 als[3*4096];    // A (weights) triple buffer, 128co x 32ch each
  __shared__ u16 pnl[2*6144];    // H panel double buffer, 192 rows x 32ch each

  int bid = blockIdx.x;
  int co_half = (bid >> 3) & 1;                 // pair same-ptile blocks 8 apart (same XCD)
  int ptile = (bid & 7) | ((bid >> 4) << 3);
  int p0 = ptile * 128;
  int b = p0 >> 16;
  int pib0 = p0 & (POSB-1);
  int nb0 = pib0 >> 4;                          // 8 n's per block

  int t = threadIdx.x;
  int lane = t & 63, wave = t >> 6;
  int wr = wave >> 1, wc = wave & 1;
  int co_base = co_half*128;
  int l15 = lane & 15, l4 = lane >> 4;

  const u16* xb = xt + ((size_t)b)*NN*CIN;
  const u16* yb = yt + ((size_t)b)*NN*CIN;

  // A staging geometry: lane covers rows r0,r1 (16B each), inverse-swizzled source
  int r0 = wave*32 + (lane>>2);
  int r1 = r0 + 16;
  int ch0 = (lane&3) ^ ((r0>>1)&3);
  int ch1 = (lane&3) ^ ((r1>>1)&3);
  int wuni = __builtin_amdgcn_readfirstlane(wave);
  int wu  = wuni*1024;          // A-stage wave slice (elems)
  int wu2 = wuni*512;           // panel-stage wave slice (elems)
  const u16* pA0 = wp + (size_t)(co_base + r0)*CK + ch0*8;
  const u16* pA1 = wp + (size_t)(co_base + r1)*CK + ch1*8;

  // ---- panel gather pointers, computed ONCE per block (3 tasks/thread)
  const u16 *xp[3], *yp[3];
  { int tq4 = t >> 2;
    #pragma unroll
    for (int i=0;i<3;++i){
      int row = i*64 + tq4;                      // 0..191
      int lc = (t&3) ^ ((row>>1)&3);             // inverse swizzle chunk
      int q = (row*57) >> 10;                    // row/18 (row<192)
      int kk = row - q*18 - 1;                   // -1..16
      int n2 = nb0 - 1 + q;
      bool valid = (row < 180) && ((unsigned)n2 < (unsigned)NN) && ((unsigned)kk < (unsigned)KPTS);
      int j0 = 0, j1 = 0;
      if (valid){ int eo = b*POSB + n2*16 + kk; j0 = e[eo]; j1 = e[TOTPOS + eo]; }
      xp[i] = (valid ? xb + (size_t)j1*CIN : zrow) + lc*8;   // x via edge_index[1]
      yp[i] = (valid ? yb + (size_t)j0*CIN : zrow) + lc*8;   // y via edge_index[0]
    }
  }

  auto G16 = [&](const u16* g, u16* l){
    __builtin_amdgcn_global_load_lds((const __attribute__((address_space(1))) u32*)g,
                                     (__attribute__((address_space(3))) u32*)l, 16, 0, 0);
  };

  f32x4 acc[4][4];
  #pragma unroll
  for (int i=0;i<4;++i)
    #pragma unroll
    for (int j=0;j<4;++j) acc[i][j] = (f32x4){0.f,0.f,0.f,0.f};

  // prologue issue order: P0(3), P1(3), A0(2), A1(2), A2(2)
  G16(xp[0],    &pnl[wu2]);
  G16(xp[1],    &pnl[2048+wu2]);
  G16(xp[2],    &pnl[4096+wu2]);
  G16(xp[0]+32, &pnl[6144+wu2]);
  G16(xp[1]+32, &pnl[6144+2048+wu2]);
  G16(xp[2]+32, &pnl[6144+4096+wu2]);
  G16(pA0,      &als[wu]);      G16(pA1,      &als[wu+512]);
  G16(pA0+256,  &als[4096+wu]); G16(pA1+256,  &als[4096+wu+512]);
  G16(pA0+512,  &als[8192+wu]); G16(pA1+512,  &als[8192+wu+512]);

  int aoff[4];
  #pragma unroll
  for (int f=0; f<4; ++f) aoff[f] = SWZ(wr*64 + f*16 + l15, l4);
  int wc72l15 = wc*72 + l15;

  for (int c = 0; c < 8; ++c){
    const u16* pb = pnl + (c&1)*6144;
    int ca = c*32;
    int cc = (c < 7) ? (c+1) : 0;
    const u16 *q0,*q1,*q2;
    if (cc < 4){ q0 = xp[0]+cc*32;     q1 = xp[1]+cc*32;     q2 = xp[2]+cc*32; }
    else       { q0 = yp[0]+(cc-4)*32; q1 = yp[1]+(cc-4)*32; q2 = yp[2]+(cc-4)*32; }
    int pdst = (cc&1)*6144;
    bool doP = (c >= 1) & (c <= 6);             // P_1 prologued; P_8 doesn't exist
    #pragma unroll
    for (int tap = 0; tap < 9; ++tap){
      asm volatile("s_waitcnt vmcnt(4)" ::: "memory");
      __builtin_amdgcn_s_barrier();             // A[cur] (and panel at tap0) landed in all waves
      int abase = (tap%3)*4096;
      bf16x8 af[4], bv[4];
      #pragma unroll
      for (int f=0; f<4; ++f) af[f] = *(bf16x8*)&als[abase + aoff[f]];
      int kbc = (tap/3)*18 + (tap%3);           // (1+dn)*18 + (1+dk)
      #pragma unroll
      for (int f=0; f<4; ++f){
        int r = wc72l15 + kbc + f*18;           // panel row, 16 contiguous per fragment
        bv[f] = *(bf16x8*)&pb[r*32 + ((l4 ^ ((r>>1)&3))<<3)];
      }
      asm volatile("s_waitcnt lgkmcnt(0)" ::: "memory");
      __builtin_amdgcn_sched_barrier(0);
      __builtin_amdgcn_s_barrier();             // all reads done -> safe to overwrite
      int koff = ((tap+3)%9)*256 + ca + ((tap>5)?32:0);   // A_{s+3}; dummy at very end (harmless)
      G16(pA0 + koff, &als[abase + wu]);
      G16(pA1 + koff, &als[abase + wu + 512]);
      if (tap == 0 && doP){                     // panel for chunk c+1
        G16(q0, &pnl[pdst + wu2]);
        G16(q1, &pnl[pdst + 2048 + wu2]);
        G16(q2, &pnl[pdst + 4096 + wu2]);
      }
      __builtin_amdgcn_s_setprio(1);
      #pragma unroll
      for (int fm=0; fm<4; ++fm)
        #pragma unroll
        for (int fn=0; fn<4; ++fn)
          acc[fm][fn] = __builtin_amdgcn_mfma_f32_16x16x32_bf16(af[fm], bv[fn], acc[fm][fn], 0, 0, 0);
      __builtin_amdgcn_s_setprio(0);
    }
  }
  asm volatile("s_waitcnt vmcnt(0)" ::: "memory");   // drain dummy stages before LDS reuse
  __builtin_amdgcn_s_barrier();

  // ---- epilogue: bias + max over k (l15) + per-channel sum/sumsq
  float* fs = (float*)&als[0];           // fs[0..128) = sum, fs[128..256) = sumsq
  fs[t & 255] = 0.f;
  __syncthreads();

  #pragma unroll
  for (int fm=0; fm<4; ++fm){
    #pragma unroll
    for (int j=0; j<4; ++j){
      int ch = wr*64 + fm*16 + l4*4 + j;
      int co_g = co_base + ch;
      float bv2 = bias[co_g];
      float s = 0.f, q = 0.f;
      float mv[4];
      #pragma unroll
      for (int fn=0; fn<4; ++fn){
        float v = acc[fm][fn][j] + bv2;
        s += v; q += v*v; mv[fn] = v;
      }
      #pragma unroll
      for (int o=1; o<16; o<<=1){
        s += __shfl_xor(s, o, 64);
        q += __shfl_xor(q, o, 64);
        #pragma unroll
        for (int fn=0; fn<4; ++fn) mv[fn] = fmaxf(mv[fn], __shfl_xor(mv[fn], o, 64));
      }
      if (l15 == 0){
        atomicAdd(&fs[ch], s);
        atomicAdd(&fs[128 + ch], q);
        size_t rowb = ((size_t)(b*COUT + co_g)) << 12;
        #pragma unroll
        for (int fn=0; fn<4; ++fn)
          maxout[rowb + nb0 + wc*4 + fn] = mv[fn];
      }
    }
  }
  __syncthreads();
  if (t < 128)      atomicAdd(&ssum[co_base + t], fs[t]);
  else if (t < 256) atomicAdd(&ssq[co_base + t - 128], fs[t]);
}

// ---- 4. finalize BN scale/shift
__global__ void finalize_stats_kernel(const float* __restrict__ ssum, const float* __restrict__ ssq,
                                      const float* __restrict__ gamma, const float* __restrict__ beta,
                                      float* __restrict__ scale, float* __restrict__ shift){
  int co = threadIdx.x;
  float inv = 1.0f / (float)TOTPOS;
  float mean = ssum[co]*inv;
  float var = ssq[co]*inv - mean*mean;
  float sc = gamma[co] * rsqrtf(var + 1e-5f);
  scale[co] = sc;
  shift[co] = beta[co] - mean*sc;
}

// ---- 5. in-place BN + ReLU on maxout (valid since scale>0)
__global__ void bn_finish_kernel(float* __restrict__ out, const float* __restrict__ scale,
                                 const float* __restrict__ shift){
  int t = blockIdx.x*256 + threadIdx.x;
  int co = (t >> 12) & 255;
  float v = out[t];
  out[t] = fmaxf(fmaf(scale[co], v, shift[co]), 0.f);
}

extern "C" void kernel_launch(void* const* d_in, const int* in_sizes, int n_in,
                              void* d_out, int out_size, void* d_ws, size_t ws_size,
                              hipStream_t stream){
  const float* x = (const float*)d_in[0];
  const float* y = (const float*)d_in[1];
  const int*   e = (const int*)d_in[2];
  const float* w = (const float*)d_in[3];
  const float* bias = (const float*)d_in[4];
  const float* gamma = (const float*)d_in[5];
  const float* beta  = (const float*)d_in[6];
  float* out = (float*)d_out;

  char* ws = (char*)d_ws;                  // total footprint: ~9.6 MB
  u16*   wp    = (u16*)(ws);               // 1,179,648 B
  float* ssum  = (float*)(ws + 1179648);   // 1 KB
  float* ssq   = (float*)(ws + 1180672);   // 1 KB
  u16*   zrow  = (u16*)(ws + 1181696);     // 1 KB zero row
  float* scale = (float*)(ws + 1182720);   // 1 KB
  float* shift = (float*)(ws + 1183744);   // 1 KB
  u16*   xt    = (u16*)(ws + 1184768);     // 4 MB
  u16*   yt    = (u16*)(ws + 5379072);     // 4 MB  (end: 9,573,376)

  hipMemsetAsync(ssum, 0, 3072, stream);   // zero ssum+ssq+zrow every call (deterministic)

  pack_w_kernel<<<2304, 256, 0, stream>>>(w, wp);
  dim3 tg(NN/64, CIN/32, NB);
  transpose_cast_kernel<<<tg, 256, 0, stream>>>(x, y, xt, yt);
  conv_gemm_kernel<<<4096, 256, 0, stream>>>(wp, e, xt, yt, zrow, bias, ssum, ssq, out);
  finalize_stats_kernel<<<1, COUT, 0, stream>>>(ssum, ssq, gamma, beta, scale, shift);
  bn_finish_kernel<<<out_size/256, 256, 0, stream>>>(out, scale, shift);
}